// Round 7
// baseline (3753.418 us; speedup 1.0000x reference)
//
#include <hip/hip_runtime.h>
#include <math.h>

#define BATCH   512
#define N       128
#define DDIM    1024
#define NITER   30
#define SIGMA_C 0.1f
#define EPS_C   1e-6f
#define MPAD    132
#define BSTR4   65            // float4 stride per 16x16 block
#define BSTRF   (BSTR4 * 4)   // 260 floats

// packed lower-triangle block id (bi >= bj)
__device__ __forceinline__ int blkid(int bi, int bj) { return ((bi * (bi + 1)) >> 1) + bj; }
// float offset of element (rin, cin) inside block blk (f4-slot XOR swizzle)
__device__ __forceinline__ int eoff(int blk, int rin, int cin) {
    return blk * BSTRF + rin * 16 + ((((cin >> 2) ^ (rin >> 2)) & 3) << 2) + (cin & 3);
}
// float4 offset for slot s (= cin>>2)
__device__ __forceinline__ int f4off(int blk, int rin, int s) {
    return blk * BSTR4 + rin * 4 + ((s ^ (rin >> 2)) & 3);
}

// ---------------- Kernel A: Q = 2*(X X^T + eps I) ----------------
__global__ __launch_bounds__(256) void gram_kernel(const float* __restrict__ X,
                                                   float* __restrict__ Q) {
    const int b = blockIdx.x;
    const float* Xb = X + (size_t)b * N * DDIM;
    float* Qb = Q + (size_t)b * N * N;

    __shared__ float Xs[16][MPAD];
    const int t  = threadIdx.x;
    const int tx = t & 15, ty = t >> 4;
    const int li = t >> 1;
    const int lk = (t & 1) * 8;

    float acc[8][8];
#pragma unroll
    for (int u = 0; u < 8; ++u)
#pragma unroll
        for (int v = 0; v < 8; ++v) acc[u][v] = 0.0f;

    for (int k0 = 0; k0 < DDIM; k0 += 16) {
        const float4 p0 = *(const float4*)(Xb + (size_t)li * DDIM + k0 + lk);
        const float4 p1 = *(const float4*)(Xb + (size_t)li * DDIM + k0 + lk + 4);
        __syncthreads();
        Xs[lk + 0][li] = p0.x; Xs[lk + 1][li] = p0.y;
        Xs[lk + 2][li] = p0.z; Xs[lk + 3][li] = p0.w;
        Xs[lk + 4][li] = p1.x; Xs[lk + 5][li] = p1.y;
        Xs[lk + 6][li] = p1.z; Xs[lk + 7][li] = p1.w;
        __syncthreads();
#pragma unroll
        for (int kk = 0; kk < 16; ++kk) {
            float4 A0 = *(const float4*)&Xs[kk][ty * 8];
            float4 A1 = *(const float4*)&Xs[kk][ty * 8 + 4];
            float4 C0 = *(const float4*)&Xs[kk][tx * 8];
            float4 C1 = *(const float4*)&Xs[kk][tx * 8 + 4];
            float a[8] = {A0.x, A0.y, A0.z, A0.w, A1.x, A1.y, A1.z, A1.w};
            float c[8] = {C0.x, C0.y, C0.z, C0.w, C1.x, C1.y, C1.z, C1.w};
#pragma unroll
            for (int u = 0; u < 8; ++u)
#pragma unroll
                for (int v = 0; v < 8; ++v) acc[u][v] += a[u] * c[v];
        }
    }
#pragma unroll
    for (int u = 0; u < 8; ++u) {
        const int i = ty * 8 + u;
#pragma unroll
        for (int v = 0; v < 8; ++v) {
            const int k = tx * 8 + v;
            acc[u][v] = 2.0f * acc[u][v] + ((i == k) ? 2.0f * EPS_C : 0.0f);
        }
        float4 o0, o1;
        o0.x = acc[u][0]; o0.y = acc[u][1]; o0.z = acc[u][2]; o0.w = acc[u][3];
        o1.x = acc[u][4]; o1.y = acc[u][5]; o1.z = acc[u][6]; o1.w = acc[u][7];
        *(float4*)(Qb + (size_t)i * N + tx * 8)     = o0;
        *(float4*)(Qb + (size_t)i * N + tx * 8 + 4) = o1;
    }
}

// ---------------- Kernel B: IPM, 1 item / 256-thread block (4 waves) ----------------
// Packed lower triangle (36 x 16x16 swizzled blocks, 37.4 KB) in LDS; Q reloaded
// from global (L2/L3) each iteration. qa computed from global Q rows (coalesced).
// Forward: blocked Cholesky, RHS trailing overlapped with next diag factor.
// Backward: blocked; 16-step shfl transpose-solve (both RHS on 32 lanes) +
// parallel 256-thread trailing update per panel.
__global__ __launch_bounds__(256) void ipm_solo(const float* __restrict__ Q,
                                                float* __restrict__ alphas) {
    __shared__ __align__(16) float M[36 * BSTRF];
    __shared__ __align__(16) float av[N], lam[N], dinv[N], rh0[N], rh1[N];
    __shared__ __align__(16) float part[256];
    __shared__ float xp0[16], xp1[16];
    __shared__ float scal[8];   // 0,1: sum_a halves  2,3: sum_al halves  4,5: rhs sums  6,7: step ratios

    const int t    = threadIdx.x;
    const int wave = t >> 6;
    const int lane = t & 63;
    const int b    = blockIdx.x;
    const float* Qb = Q + (size_t)b * N * N;

    // per-thread reload offsets (hoisted out of the iteration loop)
    int offL[9], offG[9];
#pragma unroll
    for (int p = 0; p < 9; ++p) {
        const int f4  = t + (p << 8);           // 0..2303
        const int blk = f4 >> 6;
        int bi = (int)(0.5f * (sqrtf(8.0f * (float)blk + 1.0f) - 1.0f));
        if ((((bi + 1) * (bi + 2)) >> 1) <= blk) ++bi;
        if (((bi * (bi + 1)) >> 1) > blk) --bi;
        const int bj  = blk - ((bi * (bi + 1)) >> 1);
        const int rin = (f4 >> 2) & 15;
        const int sl  = f4 & 3;
        offL[p] = f4off(blk, rin, sl);
        offG[p] = (bi * 16 + rin) * N + bj * 16 + (sl << 2);
    }

    float pp = 0.0f;
    if (t < N) {
        av[t]  = 1.0f / 128.0f;
        lam[t] = 1.0f;
        pp = -0.5f * Qb[(size_t)t * N + t];
    }
    if (t == 0) { scal[0] = 0.5f; scal[1] = 0.5f; scal[2] = 0.5f; scal[3] = 0.5f; }
    float nu = 0.0f;
    __syncthreads();

#pragma unroll 1
    for (int iter = 0; iter < NITER; ++iter) {
        // ---- reload packed triangle + qa (global row dot), overlapped ----
#pragma unroll
        for (int p = 0; p < 9; ++p)
            ((float4*)M)[offL[p]] = *(const float4*)(Qb + offG[p]);
        {
            const int r = t >> 1, h2 = t & 1;
            const float* qr = Qb + (size_t)r * N + (h2 << 6);
            float qs = 0.0f;
#pragma unroll
            for (int s = 0; s < 16; ++s) {
                const float4 m4 = *(const float4*)(qr + (s << 2));
                const float4 a4 = *(const float4*)&av[(h2 << 6) + (s << 2)];
                qs = fmaf(m4.x, a4.x, qs); qs = fmaf(m4.y, a4.y, qs);
                qs = fmaf(m4.z, a4.z, qs); qs = fmaf(m4.w, a4.w, qs);
            }
            part[t] = qs;
        }
        __syncthreads();                                    // B1
        const float r_pri = scal[0] + scal[1] - 1.0f;
        const float mu    = (scal[2] + scal[3]) * (1.0f / 128.0f);
        if (t < N) {
            const float ai = av[t], li = lam[t];
            const float qa = part[2 * t] + part[2 * t + 1];
            rh0[t] = -(qa + pp + nu - SIGMA_C * mu / ai);
            rh1[t] = 1.0f;
            M[eoff(blkid(t >> 4, t >> 4), t & 15, t & 15)] += li / ai;
        }
        __syncthreads();                                    // B2

        // ================= forward: 8 panels =================
#pragma unroll 1
        for (int jb = 0; jb < 8; ++jb) {
            const int j0 = jb << 4;
            // phase A: wave0 diag factor ; wave1 rhs-trailing of panel jb-1
            if (wave == 0) {
                const int dblk = blkid(jb, jb);
                float row[16];
                float myri = 0.0f;
                if (lane < 16) {
#pragma unroll
                    for (int c = 0; c < 16; ++c) row[c] = M[eoff(dblk, lane, c)];
                } else {
#pragma unroll
                    for (int c = 0; c < 16; ++c) row[c] = 1.0f;
                }
#pragma unroll
                for (int c = 0; c < 16; ++c) {
                    const float d   = __shfl(row[c], c);
                    const float riv = rsqrtf(d);
                    if (lane == c) { row[c] = d * riv; myri = riv; }
                    const float lv = (lane > c && lane < 16) ? row[c] * riv : 0.0f;
                    if (lane > c && lane < 16) row[c] = lv;
#pragma unroll
                    for (int k = c + 1; k < 16; ++k) row[k] -= lv * __shfl(lv, k);
                }
                if (lane < 16) {
#pragma unroll
                    for (int c = 0; c < 16; ++c)
                        if (c <= lane) M[eoff(dblk, lane, c)] = row[c];
                    dinv[j0 + lane] = myri;
                }
            } else if (wave == 1 && jb > 0) {
                const int jp = j0 - 16;
                float y0[16], y1[16];
#pragma unroll
                for (int m = 0; m < 16; ++m) { y0[m] = rh0[jp + m]; y1[m] = rh1[jp + m]; }
#pragma unroll
                for (int rep = 0; rep < 2; ++rep) {
                    const int j = j0 + lane + (rep << 6);
                    if (j < N) {
                        const int lb = blkid(j >> 4, jb - 1);
                        const int jr = j & 15;
                        float s0 = 0.0f, s1 = 0.0f;
#pragma unroll
                        for (int m = 0; m < 16; ++m) {
                            const float lv = M[eoff(lb, jr, m)];
                            s0 = fmaf(lv, y0[m], s0);
                            s1 = fmaf(lv, y1[m], s1);
                        }
                        rh0[j] -= s0; rh1[j] -= s1;
                    }
                }
            }
            __syncthreads();                                // Ba
            // phase B: TRSM, one row per thread (+2 rhs rows)
            {
                const int cnt = 112 - j0;
                if (t < cnt + 2) {
                    const bool mrow = (t < cnt);
                    const int i  = j0 + 16 + t;
                    const int ib = mrow ? blkid(i >> 4, jb) : 0;
                    const int ir = i & 15;
                    float w[16];
                    if (mrow) {
#pragma unroll
                        for (int sl = 0; sl < 4; ++sl)
                            *(float4*)&w[sl << 2] = ((const float4*)M)[f4off(ib, ir, sl)];
                    } else {
                        const float* rp = (t == cnt) ? rh0 : rh1;
#pragma unroll
                        for (int c = 0; c < 16; ++c) w[c] = rp[j0 + c];
                    }
                    const int dblk = blkid(jb, jb);
#pragma unroll
                    for (int c = 0; c < 16; ++c) {
                        float sv = w[c];
#pragma unroll
                        for (int m = 0; m < c; ++m) sv -= w[m] * M[eoff(dblk, c, m)];
                        w[c] = sv * dinv[j0 + c];
                    }
                    if (mrow) {
#pragma unroll
                        for (int sl = 0; sl < 4; ++sl)
                            ((float4*)M)[f4off(ib, ir, sl)] = *(const float4*)&w[sl << 2];
                    } else {
                        float* rp = (t == cnt) ? rh0 : rh1;
#pragma unroll
                        for (int c = 0; c < 16; ++c) rp[j0 + c] = w[c];
                    }
                }
            }
            __syncthreads();                                // Bb
            // phase C: trailing SYRK (64x16 tiles, 4-way wave split)
            if (jb < 7) {
                const int rg = lane >> 2, cg = lane & 3;
                int tc = 0;
#pragma unroll 1
                for (int R0 = j0 + 16; R0 < 128; R0 += 64) {
                    const int i0 = R0 + (rg << 2);
                    int cmax = R0 + 63; if (cmax > 112) cmax = 112;
#pragma unroll 1
                    for (int C0 = j0 + 16; C0 <= cmax; C0 += 16) {
                        if (((tc++) & 3) != wave) continue;
                        if (i0 >= 128) continue;
                        const int rin = i0 & 15;
                        const int bA  = blkid(i0 >> 4, jb);
                        const int bj  = C0 >> 4;
                        const int bB  = blkid(bj, jb);
                        const int bC  = blkid(i0 >> 4, bj);
                        float acc[4][4];
#pragma unroll
                        for (int u = 0; u < 4; ++u)
#pragma unroll
                            for (int v = 0; v < 4; ++v) acc[u][v] = 0.0f;
#pragma unroll
                        for (int m4 = 0; m4 < 4; ++m4) {
                            float4 A[4], B[4];
#pragma unroll
                            for (int u = 0; u < 4; ++u)
                                A[u] = ((const float4*)M)[f4off(bA, rin + u, m4)];
#pragma unroll
                            for (int v = 0; v < 4; ++v)
                                B[v] = ((const float4*)M)[f4off(bB, (cg << 2) + v, m4)];
#pragma unroll
                            for (int u = 0; u < 4; ++u)
#pragma unroll
                                for (int v = 0; v < 4; ++v) {
                                    acc[u][v] = fmaf(A[u].x, B[v].x, acc[u][v]);
                                    acc[u][v] = fmaf(A[u].y, B[v].y, acc[u][v]);
                                    acc[u][v] = fmaf(A[u].z, B[v].z, acc[u][v]);
                                    acc[u][v] = fmaf(A[u].w, B[v].w, acc[u][v]);
                                }
                        }
                        if ((i0 >> 4) > bj) {
#pragma unroll
                            for (int u = 0; u < 4; ++u) {
                                const int ix = f4off(bC, rin + u, cg);
                                float4 cc = ((const float4*)M)[ix];
                                cc.x -= acc[u][0]; cc.y -= acc[u][1];
                                cc.z -= acc[u][2]; cc.w -= acc[u][3];
                                ((float4*)M)[ix] = cc;
                            }
                        } else {
#pragma unroll
                            for (int u = 0; u < 4; ++u) {
                                const int i = i0 + u;
#pragma unroll
                                for (int v = 0; v < 4; ++v) {
                                    const int c = C0 + (cg << 2) + v;
                                    if (c <= i) M[eoff(bC, rin + u, (cg << 2) + v)] -= acc[u][v];
                                }
                            }
                        }
                    }
                }
                __syncthreads();                            // Bc
            }
        }

        // ================= backward: blocked L^T x = y =================
#pragma unroll 1
        for (int jb = 7; jb >= 0; --jb) {
            const int j0 = jb << 4;
            if (wave == 0 && lane < 32) {                   // both rhs on lanes 0..31
                const int g = lane >> 4, c = lane & 15;
                float* rp = g ? rh1 : rh0;
                const int dblk = blkid(jb, jb);
                const float di = dinv[j0 + c];
                float acc = rp[j0 + c];
                float x = 0.0f;
#pragma unroll
                for (int m = 15; m >= 0; --m) {
                    if (c == m) x = acc * di;
                    const float xm = __shfl(x, (g << 4) + m);
                    if (c < m) acc -= M[eoff(dblk, m, c)] * xm;
                }
                rp[j0 + c] = x;
                (g ? xp1 : xp0)[c] = x;
            }
            __syncthreads();
            if (jb > 0) {
                const int g = t >> 7, j = t & 127;
                if (j < j0) {
                    const float* xg = g ? xp1 : xp0;
                    const int blk = blkid(jb, j >> 4);
                    const int cin = j & 15;
                    float s = 0.0f;
#pragma unroll
                    for (int m = 0; m < 16; ++m)
                        s = fmaf(M[eoff(blk, m, cin)], xg[m], s);
                    (g ? rh1 : rh0)[j] -= s;
                }
                __syncthreads();
            }
        }

        // ================= epilogue =================
        if (wave < 2) {                                     // rhs sums for dnu
            const float* rp = wave ? rh1 : rh0;
            float s = rp[lane] + rp[lane + 64];
#pragma unroll
            for (int o = 32; o; o >>= 1) s += __shfl_xor(s, o);
            if (lane == 0) scal[4 + wave] = s;
        }
        __syncthreads();
        const float dnu = (scal[4] + r_pri) / scal[5];
        if (t < N) {
            const float x0 = rh0[t], x1 = rh1[t];
            const float ai = av[t], li = lam[t];
            const float da = x0 - dnu * x1;
            const float dl = -li + SIGMA_C * mu / ai - li * da / ai;
            float rr = 3.4e38f;
            if (da < 0.0f) rr = fminf(rr, -ai / da);
            if (dl < 0.0f) rr = fminf(rr, -li / dl);
#pragma unroll
            for (int o = 32; o; o >>= 1) rr = fminf(rr, __shfl_xor(rr, o));
            if (lane == 0) scal[6 + wave] = rr;
            rh0[t] = da; rh1[t] = dl;
        }
        __syncthreads();
        const float ts = fminf(1.0f, 0.99f * fminf(scal[6], scal[7]));
        nu += ts * dnu;
        if (t < N) {
            const float na = av[t] + ts * rh0[t];
            const float nl = lam[t] + ts * rh1[t];
            av[t] = na; lam[t] = nl;
            float sa = na, sal = na * nl;
#pragma unroll
            for (int o = 32; o; o >>= 1) { sa += __shfl_xor(sa, o); sal += __shfl_xor(sal, o); }
            if (lane == 0) { scal[0 + wave] = sa; scal[2 + wave] = sal; }
        }
        __syncthreads();
    }

    if (t < N) alphas[(size_t)b * N + t] = av[t];
}

// ---------------- Kernel C: centers = alpha^T X ----------------
__global__ __launch_bounds__(256) void centers_kernel(const float* __restrict__ X,
                                                      const float* __restrict__ alphas,
                                                      float* __restrict__ out) {
    const int b = blockIdx.x;
    __shared__ float al[N];
    const int t = threadIdx.x;
    if (t < N) al[t] = alphas[(size_t)b * N + t];
    __syncthreads();
    const float* Xb = X + (size_t)b * N * DDIM;
    float acc0 = 0.0f, acc1 = 0.0f, acc2 = 0.0f, acc3 = 0.0f;
    for (int s = 0; s < N; ++s) {
        const float a = al[s];
        const float* row = Xb + (size_t)s * DDIM + t;
        acc0 += a * row[0];
        acc1 += a * row[256];
        acc2 += a * row[512];
        acc3 += a * row[768];
    }
    float* ob = out + (size_t)b * DDIM + t;
    ob[0]   = acc0;
    ob[256] = acc1;
    ob[512] = acc2;
    ob[768] = acc3;
}

extern "C" void kernel_launch(void* const* d_in, const int* in_sizes, int n_in,
                              void* d_out, int out_size, void* d_ws, size_t ws_size,
                              hipStream_t stream) {
    (void)in_sizes; (void)n_in; (void)out_size; (void)ws_size;
    const float* X = (const float*)d_in[0];
    float* out = (float*)d_out;
    float* Q = (float*)d_ws;                       // 512*128*128 f32 = 32 MB
    float* alphas = Q + (size_t)BATCH * N * N;     // + 256 KB
    gram_kernel<<<dim3(BATCH), dim3(256), 0, stream>>>(X, Q);
    ipm_solo<<<dim3(BATCH), dim3(256), 0, stream>>>(Q, alphas);
    centers_kernel<<<dim3(BATCH), dim3(256), 0, stream>>>(X, alphas, out);
}

// Round 8
// 1859.769 us; speedup vs baseline: 2.0182x; 2.0182x over previous
//
#include <hip/hip_runtime.h>
#include <math.h>

#define BATCH   512
#define N       128
#define DDIM    1024
#define NITER   30
#define NCG     24
#define SIGMA_C 0.1f
#define EPS_C   1e-6f
#define MPAD    132

// ---------------- Kernel A: Q = 2*(X X^T + eps I) ----------------
__global__ __launch_bounds__(256) void gram_kernel(const float* __restrict__ X,
                                                   float* __restrict__ Q) {
    const int b = blockIdx.x;
    const float* Xb = X + (size_t)b * N * DDIM;
    float* Qb = Q + (size_t)b * N * N;

    __shared__ float Xs[16][MPAD];
    const int t  = threadIdx.x;
    const int tx = t & 15, ty = t >> 4;
    const int li = t >> 1;
    const int lk = (t & 1) * 8;

    float acc[8][8];
#pragma unroll
    for (int u = 0; u < 8; ++u)
#pragma unroll
        for (int v = 0; v < 8; ++v) acc[u][v] = 0.0f;

    for (int k0 = 0; k0 < DDIM; k0 += 16) {
        const float4 p0 = *(const float4*)(Xb + (size_t)li * DDIM + k0 + lk);
        const float4 p1 = *(const float4*)(Xb + (size_t)li * DDIM + k0 + lk + 4);
        __syncthreads();
        Xs[lk + 0][li] = p0.x; Xs[lk + 1][li] = p0.y;
        Xs[lk + 2][li] = p0.z; Xs[lk + 3][li] = p0.w;
        Xs[lk + 4][li] = p1.x; Xs[lk + 5][li] = p1.y;
        Xs[lk + 6][li] = p1.z; Xs[lk + 7][li] = p1.w;
        __syncthreads();
#pragma unroll
        for (int kk = 0; kk < 16; ++kk) {
            float4 A0 = *(const float4*)&Xs[kk][ty * 8];
            float4 A1 = *(const float4*)&Xs[kk][ty * 8 + 4];
            float4 C0 = *(const float4*)&Xs[kk][tx * 8];
            float4 C1 = *(const float4*)&Xs[kk][tx * 8 + 4];
            float a[8] = {A0.x, A0.y, A0.z, A0.w, A1.x, A1.y, A1.z, A1.w};
            float c[8] = {C0.x, C0.y, C0.z, C0.w, C1.x, C1.y, C1.z, C1.w};
#pragma unroll
            for (int u = 0; u < 8; ++u)
#pragma unroll
                for (int v = 0; v < 8; ++v) acc[u][v] += a[u] * c[v];
        }
    }
#pragma unroll
    for (int u = 0; u < 8; ++u) {
        const int i = ty * 8 + u;
#pragma unroll
        for (int v = 0; v < 8; ++v) {
            const int k = tx * 8 + v;
            acc[u][v] = 2.0f * acc[u][v] + ((i == k) ? 2.0f * EPS_C : 0.0f);
        }
        float4 o0, o1;
        o0.x = acc[u][0]; o0.y = acc[u][1]; o0.z = acc[u][2]; o0.w = acc[u][3];
        o1.x = acc[u][4]; o1.y = acc[u][5]; o1.z = acc[u][6]; o1.w = acc[u][7];
        *(float4*)(Qb + (size_t)i * N + tx * 8)     = o0;
        *(float4*)(Qb + (size_t)i * N + tx * 8 + 4) = o1;
    }
}

// ---------------- Kernel B: IPM with Jacobi-PCG inner solver ----------------
// One item per 256-thread block (grid 512, 2 blocks/CU). Q lives in LDS for the
// whole kernel (row stride 33 float4 -> conflict-free row dots); M = Q + diag(ds)
// is applied matrix-free, so Q is never modified (no reload, no Cholesky, no
// serial chains). Both RHS solved by a fused dual Jacobi-PCG (Chronopoulos
// single-reduction form), warm-started from the previous IPM iteration.
// Threads t<128 "own" row t (state in registers); all 256 drive the GEMV halves.
__global__ __launch_bounds__(256) void ipm_cg(const float* __restrict__ Q,
                                              float* __restrict__ alphas) {
    __shared__ __align__(16) float4 Qs[N * 33];
    __shared__ __align__(16) float u0[N], u1[N], avl[N];
    __shared__ float partQ[256], part0[256], part1[256];
    __shared__ float scal[20];

    const int t    = threadIdx.x;
    const int lane = t & 63;
    const int w    = t >> 6;          // owner waves: 0,1
    const int b    = blockIdx.x;
    const float* Qb = Q + (size_t)b * N * N;

    // ---- one-time Q load (row r halves) ----
    {
        const int r = t >> 1, h = t & 1;
        const float* src = Qb + (size_t)r * N + (h << 6);
        float4* dst = &Qs[r * 33 + (h << 4)];
#pragma unroll
        for (int s = 0; s < 16; ++s) dst[s] = *(const float4*)(src + (s << 2));
    }
    float avr = 1.0f / 128.0f, lmr = 1.0f;
    float x0 = 0.0f, x1 = 0.0f;           // warm-start solutions (persist)
    float pp = 0.0f, qd = 0.0f;
    if (t < N) {
        qd = Qb[(size_t)t * N + t];
        pp = -0.5f * qd;
        avl[t] = avr;
    }
    float nu = 0.0f;
    __syncthreads();

#pragma unroll 1
    for (int iter = 0; iter < NITER; ++iter) {
        const int rr = t >> 1, h = t & 1;
        const float4* Qr = &Qs[rr * 33 + (h << 4)];

        // ---- P0: qa = Q@a parts; owner: u := x (warm), sum_a / sum_al partials ----
        {
            const float4* A4 = (const float4*)&avl[h << 6];
            float s0 = 0.0f;
#pragma unroll
            for (int s = 0; s < 16; ++s) {
                const float4 q = Qr[s], a = A4[s];
                s0 = fmaf(q.x, a.x, s0); s0 = fmaf(q.y, a.y, s0);
                s0 = fmaf(q.z, a.z, s0); s0 = fmaf(q.w, a.w, s0);
            }
            partQ[t] = s0;
        }
        if (t < N) {
            u0[t] = x0; u1[t] = x1;
            float sa = avr, sal = avr * lmr;
#pragma unroll
            for (int o = 32; o; o >>= 1) { sa += __shfl_xor(sa, o); sal += __shfl_xor(sal, o); }
            if (lane == 0) { scal[0 + w] = sa; scal[2 + w] = sal; }
        }
        __syncthreads();                                    // B1

        // ---- P1: warm matvec A*x parts; owner: mu, rhs, Jacobi diag ----
        float mu = 0.0f, r_pri = 0.0f, ds = 0.0f, dinv = 0.0f, rhs0 = 0.0f;
        {
            const float4* U0 = (const float4*)&u0[h << 6];
            const float4* U1 = (const float4*)&u1[h << 6];
            float s0 = 0.0f, s1 = 0.0f;
#pragma unroll
            for (int s = 0; s < 16; ++s) {
                const float4 q = Qr[s];
                const float4 a = U0[s], c = U1[s];
                s0 = fmaf(q.x, a.x, s0); s0 = fmaf(q.y, a.y, s0);
                s0 = fmaf(q.z, a.z, s0); s0 = fmaf(q.w, a.w, s0);
                s1 = fmaf(q.x, c.x, s1); s1 = fmaf(q.y, c.y, s1);
                s1 = fmaf(q.z, c.z, s1); s1 = fmaf(q.w, c.w, s1);
            }
            part0[t] = s0; part1[t] = s1;
        }
        r_pri = scal[0] + scal[1] - 1.0f;
        mu    = (scal[2] + scal[3]) * (1.0f / 128.0f);
        if (t < N) {
            const float qa = partQ[2 * t] + partQ[2 * t + 1];
            ds   = lmr / avr;
            dinv = 1.0f / (qd + ds);
            rhs0 = -(qa + pp + nu - SIGMA_C * mu / avr);
        }
        __syncthreads();                                    // B2

        // ---- P2: residual, first preconditioned direction, gamma(0) ----
        float r0 = 0.0f, r1 = 0.0f, uu0 = 0.0f, uu1 = 0.0f;
        if (t < N) {
            const float ax0 = part0[2 * t] + part0[2 * t + 1] + ds * x0;
            const float ax1 = part1[2 * t] + part1[2 * t + 1] + ds * x1;
            r0 = rhs0 - ax0;
            r1 = 1.0f  - ax1;
            uu0 = dinv * r0; uu1 = dinv * r1;
            u0[t] = uu0; u1[t] = uu1;
            float g0 = r0 * uu0, g1 = r1 * uu1;
#pragma unroll
            for (int o = 32; o; o >>= 1) { g0 += __shfl_xor(g0, o); g1 += __shfl_xor(g1, o); }
            if (lane == 0) { scal[4 + w] = g0; scal[6 + w] = g1; }
        }
        __syncthreads();                                    // B3

        // ---- CG loop (Chronopoulos/Gear: 1 matvec + 1 reduction pair per step) ----
        float p0r = 0.0f, p1r = 0.0f, s0r = 0.0f, s1r = 0.0f;
        float g0old = 0.0f, g1old = 0.0f, a0old = 1.0f, a1old = 1.0f;
#pragma unroll 1
        for (int k = 0; k < NCG; ++k) {
            const int gb = 4 + 8 * (k & 1);        // gamma slots this step
            const int gn = 4 + 8 * (1 - (k & 1));  // gamma slots next step
            // S1: matvec parts of A*u
            {
                const float4* U0 = (const float4*)&u0[h << 6];
                const float4* U1 = (const float4*)&u1[h << 6];
                float s0 = 0.0f, s1 = 0.0f;
#pragma unroll
                for (int s = 0; s < 16; ++s) {
                    const float4 q = Qr[s];
                    const float4 a = U0[s], c = U1[s];
                    s0 = fmaf(q.x, a.x, s0); s0 = fmaf(q.y, a.y, s0);
                    s0 = fmaf(q.z, a.z, s0); s0 = fmaf(q.w, a.w, s0);
                    s1 = fmaf(q.x, c.x, s1); s1 = fmaf(q.y, c.y, s1);
                    s1 = fmaf(q.z, c.z, s1); s1 = fmaf(q.w, c.w, s1);
                }
                part0[t] = s0; part1[t] = s1;
            }
            __syncthreads();                                // Bs1
            // S2: owner: w = Au row; delta = u.w partials
            float w0 = 0.0f, w1 = 0.0f;
            if (t < N) {
                w0 = part0[2 * t] + part0[2 * t + 1] + ds * uu0;
                w1 = part1[2 * t] + part1[2 * t + 1] + ds * uu1;
                float d0 = uu0 * w0, d1 = uu1 * w1;
#pragma unroll
                for (int o = 32; o; o >>= 1) { d0 += __shfl_xor(d0, o); d1 += __shfl_xor(d1, o); }
                if (lane == 0) { scal[8 + w] = d0; scal[10 + w] = d1; }
            }
            __syncthreads();                                // Bs2
            // S3: uniform alpha/beta; update p,s,x,r,u; gamma' partials
            {
                const float g0 = scal[gb]     + scal[gb + 1];
                const float g1 = scal[gb + 2] + scal[gb + 3];
                const float d0 = scal[8]  + scal[9];
                const float d1 = scal[10] + scal[11];
                float be0, be1, al0, al1;
                if (k == 0) {
                    be0 = 0.0f; be1 = 0.0f;
                    al0 = (g0 > 1e-30f) ? g0 / d0 : 0.0f;
                    al1 = (g1 > 1e-30f) ? g1 / d1 : 0.0f;
                } else {
                    be0 = (g0old > 1e-30f) ? g0 / g0old : 0.0f;
                    be1 = (g1old > 1e-30f) ? g1 / g1old : 0.0f;
                    const float den0 = d0 - be0 * g0 / a0old;
                    const float den1 = d1 - be1 * g1 / a1old;
                    al0 = (g0 > 1e-30f && den0 > 1e-30f) ? g0 / den0 : 0.0f;
                    al1 = (g1 > 1e-30f && den1 > 1e-30f) ? g1 / den1 : 0.0f;
                }
                g0old = g0; g1old = g1;
                a0old = (al0 != 0.0f) ? al0 : 1.0f;
                a1old = (al1 != 0.0f) ? al1 : 1.0f;
                if (t < N) {
                    p0r = uu0 + be0 * p0r;  s0r = w0 + be0 * s0r;
                    p1r = uu1 + be1 * p1r;  s1r = w1 + be1 * s1r;
                    x0 += al0 * p0r;        r0 -= al0 * s0r;
                    x1 += al1 * p1r;        r1 -= al1 * s1r;
                    uu0 = dinv * r0;        uu1 = dinv * r1;
                    u0[t] = uu0;            u1[t] = uu1;
                    float ng0 = r0 * uu0, ng1 = r1 * uu1;
#pragma unroll
                    for (int o = 32; o; o >>= 1) { ng0 += __shfl_xor(ng0, o); ng1 += __shfl_xor(ng1, o); }
                    if (lane == 0) { scal[gn + w] = ng0; scal[gn + 2 + w] = ng1; }
                }
            }
            __syncthreads();                                // Bs3
        }

        // ---- epilogue: dnu, step length, update ----
        if (t < N) {
            float sx0 = x0, sx1 = x1;
#pragma unroll
            for (int o = 32; o; o >>= 1) { sx0 += __shfl_xor(sx0, o); sx1 += __shfl_xor(sx1, o); }
            if (lane == 0) { scal[0 + w] = sx0; scal[2 + w] = sx1; }
        }
        __syncthreads();                                    // B4
        const float dnu = (scal[0] + scal[1] + r_pri) / (scal[2] + scal[3]);
        float da = 0.0f, dl = 0.0f;
        if (t < N) {
            da = x0 - dnu * x1;
            dl = -lmr + SIGMA_C * mu / avr - lmr * da / avr;
            float rmin = 3.4e38f;
            if (da < 0.0f) rmin = fminf(rmin, -avr / da);
            if (dl < 0.0f) rmin = fminf(rmin, -lmr / dl);
#pragma unroll
            for (int o = 32; o; o >>= 1) rmin = fminf(rmin, __shfl_xor(rmin, o));
            if (lane == 0) scal[8 + w] = rmin;
        }
        __syncthreads();                                    // B5
        const float ts = fminf(1.0f, 0.99f * fminf(scal[8], scal[9]));
        nu += ts * dnu;
        if (t < N) {
            avr += ts * da;
            lmr += ts * dl;
            avl[t] = avr;
        }
        __syncthreads();                                    // B6
    }

    if (t < N) alphas[(size_t)b * N + t] = avr;
}

// ---------------- Kernel C: centers = alpha^T X ----------------
__global__ __launch_bounds__(256) void centers_kernel(const float* __restrict__ X,
                                                      const float* __restrict__ alphas,
                                                      float* __restrict__ out) {
    const int b = blockIdx.x;
    __shared__ float al[N];
    const int t = threadIdx.x;
    if (t < N) al[t] = alphas[(size_t)b * N + t];
    __syncthreads();
    const float* Xb = X + (size_t)b * N * DDIM;
    float acc0 = 0.0f, acc1 = 0.0f, acc2 = 0.0f, acc3 = 0.0f;
    for (int s = 0; s < N; ++s) {
        const float a = al[s];
        const float* row = Xb + (size_t)s * DDIM + t;
        acc0 += a * row[0];
        acc1 += a * row[256];
        acc2 += a * row[512];
        acc3 += a * row[768];
    }
    float* ob = out + (size_t)b * DDIM + t;
    ob[0]   = acc0;
    ob[256] = acc1;
    ob[512] = acc2;
    ob[768] = acc3;
}

extern "C" void kernel_launch(void* const* d_in, const int* in_sizes, int n_in,
                              void* d_out, int out_size, void* d_ws, size_t ws_size,
                              hipStream_t stream) {
    (void)in_sizes; (void)n_in; (void)out_size; (void)ws_size;
    const float* X = (const float*)d_in[0];
    float* out = (float*)d_out;
    float* Q = (float*)d_ws;                       // 512*128*128 f32 = 32 MB
    float* alphas = Q + (size_t)BATCH * N * N;     // + 256 KB
    gram_kernel<<<dim3(BATCH), dim3(256), 0, stream>>>(X, Q);
    ipm_cg<<<dim3(BATCH), dim3(256), 0, stream>>>(Q, alphas);
    centers_kernel<<<dim3(BATCH), dim3(256), 0, stream>>>(X, alphas, out);
}